// Round 1
// baseline (594.191 us; speedup 1.0000x reference)
//
#include <hip/hip_runtime.h>
#include <cstdint>
#include <cstddef>

#define BB 16
#define NN 4096
#define EE 131072
#define CIN 256
#define COUT 256

// ---------------- init ----------------
__global__ __launch_bounds__(256) void init_deg_kernel(float* __restrict__ deg) {
    int i = blockIdx.x * 256 + threadIdx.x;
    if (i < BB * NN) deg[i] = 1.0f;   // self-loop weight 1
}

__global__ __launch_bounds__(256) void init_int_kernel(int* __restrict__ counts, int* __restrict__ fill) {
    int i = blockIdx.x * 256 + threadIdx.x;
    if (i < BB * NN) { counts[i] = 0; fill[i] = 0; }
}

// ---------------- degree + histogram ----------------
__global__ __launch_bounds__(256) void deg_count_kernel(const int* __restrict__ ei, const float* __restrict__ ew,
                                                        float* __restrict__ deg, int* __restrict__ counts) {
    int idx = blockIdx.x * 256 + threadIdx.x;
    if (idx >= BB * EE) return;
    int b = idx / EE, e = idx - b * EE;
    int row = ei[(size_t)b * 2 * EE + e];
    float w = ew[(size_t)b * EE + e];
    atomicAdd(&deg[b * NN + row], w);
    atomicAdd(&counts[b * NN + row], 1);
}

__global__ __launch_bounds__(256) void deg_only_kernel(const int* __restrict__ ei, const float* __restrict__ ew,
                                                       float* __restrict__ deg) {
    int idx = blockIdx.x * 256 + threadIdx.x;
    if (idx >= BB * EE) return;
    int b = idx / EE, e = idx - b * EE;
    int row = ei[(size_t)b * 2 * EE + e];
    float w = ew[(size_t)b * EE + e];
    atomicAdd(&deg[b * NN + row], w);
}

__global__ __launch_bounds__(256) void deginv_kernel(const float* __restrict__ deg, float* __restrict__ deg_inv) {
    int i = blockIdx.x * 256 + threadIdx.x;
    if (i < BB * NN) {
        float d = deg[i];
        deg_inv[i] = (d > 0.0f) ? rsqrtf(d) : 0.0f;
    }
}

// ---------------- per-batch exclusive scan over counts (N=4096, 1024 thr x 4) ----------------
__global__ __launch_bounds__(1024) void scan_kernel(const int* __restrict__ counts, int* __restrict__ offsets) {
    int b = blockIdx.x;
    int tid = threadIdx.x;
    __shared__ int sums[1024];
    int base = b * NN + tid * 4;
    int c0 = counts[base], c1 = counts[base + 1], c2 = counts[base + 2], c3 = counts[base + 3];
    int local = c0 + c1 + c2 + c3;
    sums[tid] = local;
    __syncthreads();
    for (int off = 1; off < 1024; off <<= 1) {
        int v = (tid >= off) ? sums[tid - off] : 0;
        __syncthreads();
        sums[tid] += v;
        __syncthreads();
    }
    int excl = sums[tid] - local;
    int ob = b * (NN + 1) + tid * 4;
    offsets[ob + 0] = excl;
    offsets[ob + 1] = excl + c0;
    offsets[ob + 2] = excl + c0 + c1;
    offsets[ob + 3] = excl + c0 + c1 + c2;
    if (tid == 1023) offsets[b * (NN + 1) + NN] = sums[1023];
}

// ---------------- scatter edges into CSR slots ----------------
__global__ __launch_bounds__(256) void scatter_kernel(const int* __restrict__ ei, const float* __restrict__ ew,
                                                      const float* __restrict__ deg_inv,
                                                      const int* __restrict__ offsets, int* __restrict__ fill,
                                                      int* __restrict__ csr_col, float* __restrict__ csr_norm) {
    int idx = blockIdx.x * 256 + threadIdx.x;
    if (idx >= BB * EE) return;
    int b = idx / EE, e = idx - b * EE;
    int row = ei[(size_t)b * 2 * EE + e];
    int col = ei[(size_t)b * 2 * EE + EE + e];
    float w = ew[(size_t)b * EE + e];
    float nm = deg_inv[b * NN + row] * w * deg_inv[b * NN + col];
    int pos = offsets[b * (NN + 1) + row] + atomicAdd(&fill[b * NN + row], 1);
    csr_col[(size_t)b * EE + pos] = col;
    csr_norm[(size_t)b * EE + pos] = nm;
}

// ---------------- GEMM: xw[M=BB*NN][COUT] = x[M][CIN] @ W[CIN][COUT] ----------------
#define GTM 128
#define GTN 128
#define GKS 64
#define XLD 132  // padded leading dim (floats), 16B-aligned rows
__global__ __launch_bounds__(256) void gemm_kernel(const float* __restrict__ x, const float* __restrict__ Wm,
                                                   float* __restrict__ xw) {
    __shared__ float xs[GKS][XLD];  // [k][row]
    __shared__ float wsm[GKS][XLD]; // [k][col]
    int tid = threadIdx.x;
    int row0 = blockIdx.x * GTM;
    int col0 = blockIdx.y * GTN;
    int ty = tid >> 4, tx = tid & 15;
    float acc[8][8] = {};
    for (int kk = 0; kk < CIN; kk += GKS) {
        #pragma unroll
        for (int i = 0; i < 8; ++i) {
            int f = tid + i * 256;      // 0..2047
            int r = f >> 4;             // 0..127
            int kq = f & 15;            // 0..15 (x4 floats = 64 k)
            float4 g = *reinterpret_cast<const float4*>(&x[(size_t)(row0 + r) * CIN + kk + 4 * kq]);
            xs[4 * kq + 0][r] = g.x;
            xs[4 * kq + 1][r] = g.y;
            xs[4 * kq + 2][r] = g.z;
            xs[4 * kq + 3][r] = g.w;
        }
        #pragma unroll
        for (int i = 0; i < 8; ++i) {
            int f = tid + i * 256;
            int k = f >> 5;             // 0..63
            int cq = f & 31;            // 0..31 (x4 floats = 128 cols)
            *reinterpret_cast<float4*>(&wsm[k][4 * cq]) =
                *reinterpret_cast<const float4*>(&Wm[(size_t)(kk + k) * COUT + col0 + 4 * cq]);
        }
        __syncthreads();
        #pragma unroll 4
        for (int k = 0; k < GKS; ++k) {
            float a[8], bv[8];
            *(float4*)&a[0]  = *(const float4*)&xs[k][8 * ty];
            *(float4*)&a[4]  = *(const float4*)&xs[k][8 * ty + 4];
            *(float4*)&bv[0] = *(const float4*)&wsm[k][8 * tx];
            *(float4*)&bv[4] = *(const float4*)&wsm[k][8 * tx + 4];
            #pragma unroll
            for (int i = 0; i < 8; ++i)
                #pragma unroll
                for (int j = 0; j < 8; ++j)
                    acc[i][j] += a[i] * bv[j];
        }
        __syncthreads();
    }
    #pragma unroll
    for (int i = 0; i < 8; ++i) {
        size_t r = (size_t)row0 + 8 * ty + i;
        #pragma unroll
        for (int j4 = 0; j4 < 2; ++j4) {
            float4 o = make_float4(acc[i][4 * j4 + 0], acc[i][4 * j4 + 1],
                                   acc[i][4 * j4 + 2], acc[i][4 * j4 + 3]);
            *reinterpret_cast<float4*>(&xw[r * COUT + col0 + 8 * tx + 4 * j4]) = o;
        }
    }
}

// ---------------- CSR aggregation: one wave per output row, lane = 4 channels ----------------
__global__ __launch_bounds__(256) void aggregate_kernel(const float* __restrict__ xw, const float* __restrict__ deg_inv,
                                                        const int* __restrict__ offsets, const int* __restrict__ csr_col,
                                                        const float* __restrict__ csr_norm, float* __restrict__ out) {
    int b = blockIdx.y;
    int wave = threadIdx.x >> 6;
    int lane = threadIdx.x & 63;
    int n = blockIdx.x * 4 + wave;
    const float* xwb = xw + (size_t)b * NN * COUT;
    float di = deg_inv[b * NN + n];
    float sn = di * di;
    float4 acc = *reinterpret_cast<const float4*>(&xwb[(size_t)n * COUT + 4 * lane]);
    acc.x *= sn; acc.y *= sn; acc.z *= sn; acc.w *= sn;
    int s = offsets[b * (NN + 1) + n];
    int e = offsets[b * (NN + 1) + n + 1];
    const int* cols = csr_col + (size_t)b * EE;
    const float* norms = csr_norm + (size_t)b * EE;
    for (int i = s; i < e; ++i) {
        int col = cols[i];
        float nm = norms[i];
        float4 v = *reinterpret_cast<const float4*>(&xwb[(size_t)col * COUT + 4 * lane]);
        acc.x += nm * v.x; acc.y += nm * v.y; acc.z += nm * v.z; acc.w += nm * v.w;
    }
    float4 o = make_float4(fmaxf(acc.x, 0.f), fmaxf(acc.y, 0.f), fmaxf(acc.z, 0.f), fmaxf(acc.w, 0.f));
    *reinterpret_cast<float4*>(&out[((size_t)b * NN + n) * COUT + 4 * lane]) = o;
}

// ---------------- fallback (atomic) path, used only if ws too small for CSR ----------------
__global__ __launch_bounds__(256) void self_kernel(const float* __restrict__ xw, const float* __restrict__ deg_inv,
                                                   float* __restrict__ out) {
    int bn = blockIdx.x;             // b*NN+n
    int c = threadIdx.x;
    float di = deg_inv[bn];
    out[(size_t)bn * COUT + c] = di * di * xw[(size_t)bn * COUT + c];
}

__global__ __launch_bounds__(256) void scatter_atomic_kernel(const int* __restrict__ ei, const float* __restrict__ ew,
                                                             const float* __restrict__ deg_inv,
                                                             const float* __restrict__ xw, float* __restrict__ out) {
    int be = blockIdx.x;             // b*EE+e
    int b = be / EE, e = be - b * EE;
    int c = threadIdx.x;
    int row = ei[(size_t)b * 2 * EE + e];
    int col = ei[(size_t)b * 2 * EE + EE + e];
    float w = ew[(size_t)b * EE + e];
    float nm = deg_inv[b * NN + row] * w * deg_inv[b * NN + col];
    const float* xwb = xw + (size_t)b * NN * COUT;
    atomicAdd(&out[((size_t)b * NN + row) * COUT + c], nm * xwb[(size_t)col * COUT + c]);
}

__global__ __launch_bounds__(256) void relu_kernel(float* __restrict__ out) {
    size_t i = (size_t)blockIdx.x * 256 + threadIdx.x;
    out[i] = fmaxf(out[i], 0.0f);
}

extern "C" void kernel_launch(void* const* d_in, const int* in_sizes, int n_in,
                              void* d_out, int out_size, void* d_ws, size_t ws_size,
                              hipStream_t stream) {
    const float* x  = (const float*)d_in[0];
    const int*   ei = (const int*)d_in[1];
    const float* ew = (const float*)d_in[2];
    const float* Wm = (const float*)d_in[3];
    float* out = (float*)d_out;

    char* ws = (char*)d_ws;
    size_t off = 0;
    auto alloc = [&](size_t bytes) -> void* {
        void* p = ws + off;
        off += (bytes + 255) & ~(size_t)255;
        return p;
    };
    float* xw      = (float*)alloc((size_t)BB * NN * COUT * 4);
    float* deg     = (float*)alloc((size_t)BB * NN * 4);
    float* deg_inv = (float*)alloc((size_t)BB * NN * 4);
    int*   counts  = (int*)alloc((size_t)BB * NN * 4);
    int*   fill    = (int*)alloc((size_t)BB * NN * 4);
    int*   offsets = (int*)alloc((size_t)BB * (NN + 1) * 4);
    int*   csr_col = (int*)alloc((size_t)BB * EE * 4);
    float* csr_nrm = (float*)alloc((size_t)BB * EE * 4);
    bool use_csr = (ws_size >= off);

    const int bnBlocks = (BB * NN) / 256;       // 256
    const int beBlocks = (BB * EE) / 256;       // 8192

    init_deg_kernel<<<bnBlocks, 256, 0, stream>>>(deg);
    if (use_csr) {
        init_int_kernel<<<bnBlocks, 256, 0, stream>>>(counts, fill);
        deg_count_kernel<<<beBlocks, 256, 0, stream>>>(ei, ew, deg, counts);
    } else {
        deg_only_kernel<<<beBlocks, 256, 0, stream>>>(ei, ew, deg);
    }
    deginv_kernel<<<bnBlocks, 256, 0, stream>>>(deg, deg_inv);

    dim3 ggrid((BB * NN) / GTM, COUT / GTN);    // (512, 2)
    gemm_kernel<<<ggrid, 256, 0, stream>>>(x, Wm, xw);

    if (use_csr) {
        scan_kernel<<<BB, 1024, 0, stream>>>(counts, offsets);
        scatter_kernel<<<beBlocks, 256, 0, stream>>>(ei, ew, deg_inv, offsets, fill, csr_col, csr_nrm);
        dim3 agrid(NN / 4, BB);                 // (1024, 16)
        aggregate_kernel<<<agrid, 256, 0, stream>>>(xw, deg_inv, offsets, csr_col, csr_nrm, out);
    } else {
        self_kernel<<<BB * NN, 256, 0, stream>>>(xw, deg_inv, out);
        scatter_atomic_kernel<<<BB * EE, 256, 0, stream>>>(ei, ew, deg_inv, xw, out);
        relu_kernel<<<(BB * NN * COUT) / 256, 256, 0, stream>>>(out);
    }
}

// Round 2
// 420.774 us; speedup vs baseline: 1.4121x; 1.4121x over previous
//
#include <hip/hip_runtime.h>
#include <cstdint>
#include <cstddef>

#define BB 16
#define NN 4096
#define EE 131072
#define CIN 256
#define COUT 256

typedef __attribute__((ext_vector_type(8))) __bf16 bf16x8;
typedef __attribute__((ext_vector_type(4))) float f32x4;

// ---------------- init ----------------
__global__ __launch_bounds__(256) void init_deg_kernel(float* __restrict__ deg) {
    int i = blockIdx.x * 256 + threadIdx.x;
    if (i < BB * NN) deg[i] = 1.0f;   // self-loop weight 1
}

__global__ __launch_bounds__(256) void init_int_kernel(int* __restrict__ counts, int* __restrict__ fill) {
    int i = blockIdx.x * 256 + threadIdx.x;
    if (i < BB * NN) { counts[i] = 0; fill[i] = 0; }
}

// ---------------- W transpose + bf16 cast: wt[n][k] = (bf16)W[k][n] ----------------
__global__ __launch_bounds__(256) void cvt_wt_kernel(const float* __restrict__ W, __bf16* __restrict__ wt) {
    int n = blockIdx.x;
    int k = threadIdx.x;
    wt[n * CIN + k] = (__bf16)W[(size_t)k * COUT + n];
}

// ---------------- degree + histogram ----------------
__global__ __launch_bounds__(256) void deg_count_kernel(const int* __restrict__ ei, const float* __restrict__ ew,
                                                        float* __restrict__ deg, int* __restrict__ counts) {
    int idx = blockIdx.x * 256 + threadIdx.x;
    if (idx >= BB * EE) return;
    int b = idx / EE, e = idx - b * EE;
    int row = ei[(size_t)b * 2 * EE + e];
    float w = ew[(size_t)b * EE + e];
    atomicAdd(&deg[b * NN + row], w);
    atomicAdd(&counts[b * NN + row], 1);
}

__global__ __launch_bounds__(256) void deg_only_kernel(const int* __restrict__ ei, const float* __restrict__ ew,
                                                       float* __restrict__ deg) {
    int idx = blockIdx.x * 256 + threadIdx.x;
    if (idx >= BB * EE) return;
    int b = idx / EE, e = idx - b * EE;
    int row = ei[(size_t)b * 2 * EE + e];
    float w = ew[(size_t)b * EE + e];
    atomicAdd(&deg[b * NN + row], w);
}

__global__ __launch_bounds__(256) void deginv_kernel(const float* __restrict__ deg, float* __restrict__ deg_inv) {
    int i = blockIdx.x * 256 + threadIdx.x;
    if (i < BB * NN) {
        float d = deg[i];
        deg_inv[i] = (d > 0.0f) ? rsqrtf(d) : 0.0f;
    }
}

// ---------------- per-batch exclusive scan over counts ----------------
__global__ __launch_bounds__(1024) void scan_kernel(const int* __restrict__ counts, int* __restrict__ offsets) {
    int b = blockIdx.x;
    int tid = threadIdx.x;
    __shared__ int sums[1024];
    int base = b * NN + tid * 4;
    int c0 = counts[base], c1 = counts[base + 1], c2 = counts[base + 2], c3 = counts[base + 3];
    int local = c0 + c1 + c2 + c3;
    sums[tid] = local;
    __syncthreads();
    for (int off = 1; off < 1024; off <<= 1) {
        int v = (tid >= off) ? sums[tid - off] : 0;
        __syncthreads();
        sums[tid] += v;
        __syncthreads();
    }
    int excl = sums[tid] - local;
    int ob = b * (NN + 1) + tid * 4;
    offsets[ob + 0] = excl;
    offsets[ob + 1] = excl + c0;
    offsets[ob + 2] = excl + c0 + c1;
    offsets[ob + 3] = excl + c0 + c1 + c2;
    if (tid == 1023) offsets[b * (NN + 1) + NN] = sums[1023];
}

// ---------------- scatter edges into CSR slots ----------------
__global__ __launch_bounds__(256) void scatter_kernel(const int* __restrict__ ei, const float* __restrict__ ew,
                                                      const float* __restrict__ deg_inv,
                                                      const int* __restrict__ offsets, int* __restrict__ fill,
                                                      int* __restrict__ csr_col, float* __restrict__ csr_norm) {
    int idx = blockIdx.x * 256 + threadIdx.x;
    if (idx >= BB * EE) return;
    int b = idx / EE, e = idx - b * EE;
    int row = ei[(size_t)b * 2 * EE + e];
    int col = ei[(size_t)b * 2 * EE + EE + e];
    float w = ew[(size_t)b * EE + e];
    float nm = deg_inv[b * NN + row] * w * deg_inv[b * NN + col];
    int pos = offsets[b * (NN + 1) + row] + atomicAdd(&fill[b * NN + row], 1);
    csr_col[(size_t)b * EE + pos] = col;
    csr_norm[(size_t)b * EE + pos] = nm;
}

// ---------------- MFMA GEMM: xw[M][COUT] = bf16(x)[M][CIN] @ bf16(W)[CIN][COUT] ----------------
// 128x128 tile, BK=64, 4 waves (2x2), each wave 64x64 = 4x4 frags of 16x16x32.
// A frag layout: a[j] = A[row = lane&15][k = 8*(lane>>4) + j] (contiguous 8 bf16 -> b128 read)
// B frag layout: b[j] = B[col = lane&15][k = 8*(lane>>4) + j]  (B stored transposed: wt[n][k])
// D layout (m89-verified): D[row = (lane>>4)*4 + r][col = lane&15] = d[r]
__global__ __launch_bounds__(256) void gemm_mfma_kernel(const float* __restrict__ x, const __bf16* __restrict__ wt,
                                                        float* __restrict__ xw) {
    __shared__ __bf16 As[128][64];   // 16 KB
    __shared__ __bf16 Bs[128][64];   // 16 KB
    int tid = threadIdx.x;
    int lane = tid & 63;
    int wave = tid >> 6;
    int row0 = blockIdx.x * 128;
    int col0 = blockIdx.y * 128;
    int wr = wave >> 1, wc = wave & 1;
    int hi = lane >> 4, lo = lane & 15;
    f32x4 acc[4][4] = {};

    for (int kk = 0; kk < CIN; kk += 64) {
        // stage A: convert fp32 -> bf16 in regs, 1024 chunks of 8 elems
        #pragma unroll
        for (int j = 0; j < 4; ++j) {
            int c = j * 256 + tid;
            int r = c >> 3, kq = c & 7;
            const float* g = &x[(size_t)(row0 + r) * CIN + kk + 8 * kq];
            float4 f0 = *reinterpret_cast<const float4*>(g);
            float4 f1 = *reinterpret_cast<const float4*>(g + 4);
            bf16x8 v;
            v[0] = (__bf16)f0.x; v[1] = (__bf16)f0.y; v[2] = (__bf16)f0.z; v[3] = (__bf16)f0.w;
            v[4] = (__bf16)f1.x; v[5] = (__bf16)f1.y; v[6] = (__bf16)f1.z; v[7] = (__bf16)f1.w;
            *reinterpret_cast<bf16x8*>(&As[r][8 * kq]) = v;
        }
        // stage B (already bf16, [n][k] layout)
        #pragma unroll
        for (int j = 0; j < 4; ++j) {
            int c = j * 256 + tid;
            int r = c >> 3, kq = c & 7;
            *reinterpret_cast<bf16x8*>(&Bs[r][8 * kq]) =
                *reinterpret_cast<const bf16x8*>(&wt[(size_t)(col0 + r) * CIN + kk + 8 * kq]);
        }
        __syncthreads();
        #pragma unroll
        for (int ks = 0; ks < 2; ++ks) {
            bf16x8 a[4], b[4];
            #pragma unroll
            for (int m = 0; m < 4; ++m)
                a[m] = *reinterpret_cast<const bf16x8*>(&As[wr * 64 + m * 16 + lo][ks * 32 + 8 * hi]);
            #pragma unroll
            for (int n = 0; n < 4; ++n)
                b[n] = *reinterpret_cast<const bf16x8*>(&Bs[wc * 64 + n * 16 + lo][ks * 32 + 8 * hi]);
            #pragma unroll
            for (int m = 0; m < 4; ++m)
                #pragma unroll
                for (int n = 0; n < 4; ++n)
                    acc[m][n] = __builtin_amdgcn_mfma_f32_16x16x32_bf16(a[m], b[n], acc[m][n], 0, 0, 0);
        }
        __syncthreads();
    }
    #pragma unroll
    for (int m = 0; m < 4; ++m) {
        #pragma unroll
        for (int n = 0; n < 4; ++n) {
            #pragma unroll
            for (int r = 0; r < 4; ++r) {
                int row = row0 + wr * 64 + m * 16 + hi * 4 + r;
                int col = col0 + wc * 64 + n * 16 + lo;
                xw[(size_t)row * COUT + col] = acc[m][n][r];
            }
        }
    }
}

// ---------------- CSR aggregation: XCD-batch affinity + 4x unrolled gather ----------------
__global__ __launch_bounds__(256) void aggregate_kernel(const float* __restrict__ xw, const float* __restrict__ deg_inv,
                                                        const int* __restrict__ offsets, const int* __restrict__ csr_col,
                                                        const float* __restrict__ csr_norm, float* __restrict__ out) {
    int bid = blockIdx.x;            // 16384 blocks
    int xcd = bid & 7;               // dispatch round-robins XCDs -> pin batch pair per XCD
    int idx = bid >> 3;              // 0..2047
    int b = xcd * 2 + (idx >> 10);
    int rowblk = idx & 1023;
    int wave = threadIdx.x >> 6;
    int lane = threadIdx.x & 63;
    int n = rowblk * 4 + wave;

    const float4* xw4 = reinterpret_cast<const float4*>(xw + (size_t)b * NN * COUT);
    float di = deg_inv[b * NN + n];
    float sn = di * di;
    float4 acc = xw4[(size_t)n * 64 + lane];   // self loop
    acc.x *= sn; acc.y *= sn; acc.z *= sn; acc.w *= sn;

    int s = offsets[b * (NN + 1) + n];
    int e = offsets[b * (NN + 1) + n + 1];
    const int* cols = csr_col + (size_t)b * EE;
    const float* norms = csr_norm + (size_t)b * EE;
    int i = s;
    for (; i + 4 <= e; i += 4) {
        int c0 = cols[i], c1 = cols[i + 1], c2 = cols[i + 2], c3 = cols[i + 3];
        float m0 = norms[i], m1 = norms[i + 1], m2 = norms[i + 2], m3 = norms[i + 3];
        float4 v0 = xw4[(size_t)c0 * 64 + lane];
        float4 v1 = xw4[(size_t)c1 * 64 + lane];
        float4 v2 = xw4[(size_t)c2 * 64 + lane];
        float4 v3 = xw4[(size_t)c3 * 64 + lane];
        acc.x += m0 * v0.x + m1 * v1.x + m2 * v2.x + m3 * v3.x;
        acc.y += m0 * v0.y + m1 * v1.y + m2 * v2.y + m3 * v3.y;
        acc.z += m0 * v0.z + m1 * v1.z + m2 * v2.z + m3 * v3.z;
        acc.w += m0 * v0.w + m1 * v1.w + m2 * v2.w + m3 * v3.w;
    }
    for (; i < e; ++i) {
        int c = cols[i];
        float nm = norms[i];
        float4 v = xw4[(size_t)c * 64 + lane];
        acc.x += nm * v.x; acc.y += nm * v.y; acc.z += nm * v.z; acc.w += nm * v.w;
    }
    float4 o = make_float4(fmaxf(acc.x, 0.f), fmaxf(acc.y, 0.f), fmaxf(acc.z, 0.f), fmaxf(acc.w, 0.f));
    *reinterpret_cast<float4*>(&out[((size_t)b * NN + n) * COUT + 4 * lane]) = o;
}

// ---------------- fallback (atomic) path, used only if ws too small for CSR ----------------
__global__ __launch_bounds__(256) void self_kernel(const float* __restrict__ xw, const float* __restrict__ deg_inv,
                                                   float* __restrict__ out) {
    int bn = blockIdx.x;
    int c = threadIdx.x;
    float di = deg_inv[bn];
    out[(size_t)bn * COUT + c] = di * di * xw[(size_t)bn * COUT + c];
}

__global__ __launch_bounds__(256) void scatter_atomic_kernel(const int* __restrict__ ei, const float* __restrict__ ew,
                                                             const float* __restrict__ deg_inv,
                                                             const float* __restrict__ xw, float* __restrict__ out) {
    int be = blockIdx.x;
    int b = be / EE, e = be - b * EE;
    int c = threadIdx.x;
    int row = ei[(size_t)b * 2 * EE + e];
    int col = ei[(size_t)b * 2 * EE + EE + e];
    float w = ew[(size_t)b * EE + e];
    float nm = deg_inv[b * NN + row] * w * deg_inv[b * NN + col];
    const float* xwb = xw + (size_t)b * NN * COUT;
    atomicAdd(&out[((size_t)b * NN + row) * COUT + c], nm * xwb[(size_t)col * COUT + c]);
}

__global__ __launch_bounds__(256) void relu_kernel(float* __restrict__ out) {
    size_t i = (size_t)blockIdx.x * 256 + threadIdx.x;
    out[i] = fmaxf(out[i], 0.0f);
}

extern "C" void kernel_launch(void* const* d_in, const int* in_sizes, int n_in,
                              void* d_out, int out_size, void* d_ws, size_t ws_size,
                              hipStream_t stream) {
    const float* x  = (const float*)d_in[0];
    const int*   ei = (const int*)d_in[1];
    const float* ew = (const float*)d_in[2];
    const float* Wm = (const float*)d_in[3];
    float* out = (float*)d_out;

    char* ws = (char*)d_ws;
    size_t off = 0;
    auto alloc = [&](size_t bytes) -> void* {
        void* p = ws + off;
        off += (bytes + 255) & ~(size_t)255;
        return p;
    };
    float*  xw      = (float*)alloc((size_t)BB * NN * COUT * 4);
    __bf16* wt      = (__bf16*)alloc((size_t)CIN * COUT * 2);
    float*  deg     = (float*)alloc((size_t)BB * NN * 4);
    float*  deg_inv = (float*)alloc((size_t)BB * NN * 4);
    int*    counts  = (int*)alloc((size_t)BB * NN * 4);
    int*    fill    = (int*)alloc((size_t)BB * NN * 4);
    int*    offsets = (int*)alloc((size_t)BB * (NN + 1) * 4);
    int*    csr_col = (int*)alloc((size_t)BB * EE * 4);
    float*  csr_nrm = (float*)alloc((size_t)BB * EE * 4);
    bool use_csr = (ws_size >= off);

    const int bnBlocks = (BB * NN) / 256;       // 256
    const int beBlocks = (BB * EE) / 256;       // 8192

    cvt_wt_kernel<<<COUT, CIN, 0, stream>>>(Wm, wt);
    init_deg_kernel<<<bnBlocks, 256, 0, stream>>>(deg);
    if (use_csr) {
        init_int_kernel<<<bnBlocks, 256, 0, stream>>>(counts, fill);
        deg_count_kernel<<<beBlocks, 256, 0, stream>>>(ei, ew, deg, counts);
    } else {
        deg_only_kernel<<<beBlocks, 256, 0, stream>>>(ei, ew, deg);
    }
    deginv_kernel<<<bnBlocks, 256, 0, stream>>>(deg, deg_inv);

    dim3 ggrid((BB * NN) / 128, COUT / 128);    // (512, 2)
    gemm_mfma_kernel<<<ggrid, 256, 0, stream>>>(x, wt, xw);

    if (use_csr) {
        scan_kernel<<<BB, 1024, 0, stream>>>(counts, offsets);
        scatter_kernel<<<beBlocks, 256, 0, stream>>>(ei, ew, deg_inv, offsets, fill, csr_col, csr_nrm);
        aggregate_kernel<<<BB * NN / 4, 256, 0, stream>>>(xw, deg_inv, offsets, csr_col, csr_nrm, out);
    } else {
        self_kernel<<<BB * NN, 256, 0, stream>>>(xw, deg_inv, out);
        scatter_atomic_kernel<<<BB * EE, 256, 0, stream>>>(ei, ew, deg_inv, xw, out);
        relu_kernel<<<(BB * NN * COUT) / 256, 256, 0, stream>>>(out);
    }
}

// Round 3
// 194.232 us; speedup vs baseline: 3.0592x; 2.1664x over previous
//
#include <hip/hip_runtime.h>
#include <cstdint>
#include <cstddef>

#define BB 16
#define NN 4096
#define EE 131072
#define CIN 256
#define COUT 256
#define NCH 16
#define CHE (EE / NCH)   // 8192 edges per chunk

typedef __attribute__((ext_vector_type(8))) __bf16 bf16x8;
typedef __attribute__((ext_vector_type(4))) __bf16 bf16x4;
typedef __attribute__((ext_vector_type(4))) float f32x4;

// ---------------- init ----------------
__global__ __launch_bounds__(256) void init_deg_kernel(float* __restrict__ deg, float v) {
    int i = blockIdx.x * 256 + threadIdx.x;
    if (i < BB * NN) deg[i] = v;
}

// ---------------- W transpose + bf16 cast: wt[n][k] = (bf16)W[k][n] ----------------
__global__ __launch_bounds__(256) void cvt_wt_kernel(const float* __restrict__ W, __bf16* __restrict__ wt) {
    int n = blockIdx.x;
    int k = threadIdx.x;
    wt[n * CIN + k] = (__bf16)W[(size_t)k * COUT + n];
}

// ---------------- per-chunk LDS histogram: counts (exact) + weighted deg (coalesced atomic merge) ----------------
__global__ __launch_bounds__(256) void hist_kernel(const int* __restrict__ ei, const float* __restrict__ ew,
                                                   int* __restrict__ chist, float* __restrict__ deg) {
    __shared__ int h[NN];       // 16 KB
    __shared__ float wh[NN];    // 16 KB
    int b = blockIdx.x >> 4;          // /NCH
    int c = blockIdx.x & (NCH - 1);
    int tid = threadIdx.x;
    for (int i = tid; i < NN; i += 256) { h[i] = 0; wh[i] = 0.f; }
    __syncthreads();
    const int* rows = ei + (size_t)b * 2 * EE + (size_t)c * CHE;
    const float* w = ew + (size_t)b * EE + (size_t)c * CHE;
    #pragma unroll 4
    for (int j = 0; j < CHE / 256; ++j) {
        int row = rows[j * 256 + tid];
        float wv = w[j * 256 + tid];
        atomicAdd(&h[row], 1);
        atomicAdd(&wh[row], wv);
    }
    __syncthreads();
    int* co = chist + ((size_t)b * NCH + c) * NN;
    float* dg = deg + (size_t)b * NN;
    for (int i = tid; i < NN; i += 256) {
        co[i] = h[i];
        atomicAdd(&dg[i], wh[i]);   // coalesced contiguous atomics
    }
}

// ---------------- per-batch scan: row offsets + per-chunk bases + dinv ----------------
__global__ __launch_bounds__(1024) void scan2_kernel(const int* __restrict__ chist, const float* __restrict__ deg,
                                                     int* __restrict__ chunkbase, float* __restrict__ dinv) {
    int b = blockIdx.x, tid = threadIdx.x;
    __shared__ int sums[1024];
    int run[4];
    int carry = 0;
    for (int g = 0; g < 4; ++g) {
        int r = g * 1024 + tid;
        int tot = 0;
        #pragma unroll
        for (int c = 0; c < NCH; ++c) tot += chist[((size_t)b * NCH + c) * NN + r];
        dinv[b * NN + r] = rsqrtf(deg[b * NN + r] + 1.0f);   // +1 = self loop, always > 0
        sums[tid] = tot;
        __syncthreads();
        for (int off = 1; off < 1024; off <<= 1) {
            int v = (tid >= off) ? sums[tid - off] : 0;
            __syncthreads();
            sums[tid] += v;
            __syncthreads();
        }
        run[g] = carry + sums[tid] - tot;   // exclusive offset for row r
        carry += sums[1023];
        __syncthreads();
    }
    for (int g = 0; g < 4; ++g) {
        int acc = run[g];
        int r = g * 1024 + tid;
        #pragma unroll
        for (int c = 0; c < NCH; ++c) {
            size_t idx = ((size_t)b * NCH + c) * NN + r;
            int t = chist[idx];
            chunkbase[idx] = acc;   // chunkbase[c=0][r] == CSR row offset
            acc += t;
        }
    }
}

// ---------------- scatter into CSR slots — LDS atomics only, XCD-pinned ----------------
__global__ __launch_bounds__(256) void scatter2_kernel(const int* __restrict__ ei, const float* __restrict__ ew,
                                                       const float* __restrict__ dinv, const int* __restrict__ chunkbase,
                                                       int2* __restrict__ csr) {
    __shared__ int basebuf[NN];     // 16 KB — running slot counters
    __shared__ float dinvs[NN];     // 16 KB
    int bid = blockIdx.x;           // 256 blocks
    int xcd = bid & 7;
    int j = bid >> 3;               // 0..31
    int b = xcd * 2 + (j >> 4);
    int c = j & (NCH - 1);
    int tid = threadIdx.x;
    for (int i = tid; i < NN; i += 256) {
        basebuf[i] = chunkbase[((size_t)b * NCH + c) * NN + i];
        dinvs[i] = dinv[b * NN + i];
    }
    __syncthreads();
    const int* rows = ei + (size_t)b * 2 * EE + (size_t)c * CHE;
    const int* cols = rows + EE;
    const float* w = ew + (size_t)b * EE + (size_t)c * CHE;
    int2* cs = csr + (size_t)b * EE;
    #pragma unroll 4
    for (int jj = 0; jj < CHE / 256; ++jj) {
        int e = jj * 256 + tid;
        int row = rows[e];
        int col = cols[e];
        float nm = dinvs[row] * w[e] * dinvs[col];
        int pos = atomicAdd(&basebuf[row], 1);
        int2 pk; pk.x = col; pk.y = __float_as_int(nm);
        cs[pos] = pk;
    }
}

// ---------------- MFMA GEMM: xw(bf16)[M][COUT] = bf16(x)[M][CIN] @ bf16(W)[CIN][COUT] ----------------
__global__ __launch_bounds__(256) void gemm_mfma_kernel(const float* __restrict__ x, const __bf16* __restrict__ wt,
                                                        __bf16* __restrict__ xw) {
    __shared__ __bf16 As[128][64];   // 16 KB
    __shared__ __bf16 Bs[128][64];   // 16 KB
    int tid = threadIdx.x;
    int lane = tid & 63;
    int wave = tid >> 6;
    int row0 = blockIdx.x * 128;
    int col0 = blockIdx.y * 128;
    int wr = wave >> 1, wc = wave & 1;
    int hi = lane >> 4, lo = lane & 15;
    f32x4 acc[4][4] = {};

    for (int kk = 0; kk < CIN; kk += 64) {
        #pragma unroll
        for (int j = 0; j < 4; ++j) {
            int c = j * 256 + tid;
            int r = c >> 3, kq = c & 7;
            const float* g = &x[(size_t)(row0 + r) * CIN + kk + 8 * kq];
            float4 f0 = *reinterpret_cast<const float4*>(g);
            float4 f1 = *reinterpret_cast<const float4*>(g + 4);
            bf16x8 v;
            v[0] = (__bf16)f0.x; v[1] = (__bf16)f0.y; v[2] = (__bf16)f0.z; v[3] = (__bf16)f0.w;
            v[4] = (__bf16)f1.x; v[5] = (__bf16)f1.y; v[6] = (__bf16)f1.z; v[7] = (__bf16)f1.w;
            *reinterpret_cast<bf16x8*>(&As[r][8 * kq]) = v;
        }
        #pragma unroll
        for (int j = 0; j < 4; ++j) {
            int c = j * 256 + tid;
            int r = c >> 3, kq = c & 7;
            *reinterpret_cast<bf16x8*>(&Bs[r][8 * kq]) =
                *reinterpret_cast<const bf16x8*>(&wt[(size_t)(col0 + r) * CIN + kk + 8 * kq]);
        }
        __syncthreads();
        #pragma unroll
        for (int ks = 0; ks < 2; ++ks) {
            bf16x8 a[4], b[4];
            #pragma unroll
            for (int m = 0; m < 4; ++m)
                a[m] = *reinterpret_cast<const bf16x8*>(&As[wr * 64 + m * 16 + lo][ks * 32 + 8 * hi]);
            #pragma unroll
            for (int n = 0; n < 4; ++n)
                b[n] = *reinterpret_cast<const bf16x8*>(&Bs[wc * 64 + n * 16 + lo][ks * 32 + 8 * hi]);
            #pragma unroll
            for (int m = 0; m < 4; ++m)
                #pragma unroll
                for (int n = 0; n < 4; ++n)
                    acc[m][n] = __builtin_amdgcn_mfma_f32_16x16x32_bf16(a[m], b[n], acc[m][n], 0, 0, 0);
        }
        __syncthreads();
    }
    #pragma unroll
    for (int m = 0; m < 4; ++m)
        #pragma unroll
        for (int n = 0; n < 4; ++n)
            #pragma unroll
            for (int r = 0; r < 4; ++r) {
                int row = row0 + wr * 64 + m * 16 + hi * 4 + r;
                int col = col0 + wc * 64 + n * 16 + lo;
                xw[(size_t)row * COUT + col] = (__bf16)acc[m][n][r];
            }
}

// ---------------- CSR aggregation: bf16 gathers, XCD-pinned, 4x unroll ----------------
__global__ __launch_bounds__(256) void aggregate_kernel(const __bf16* __restrict__ xw, const float* __restrict__ dinv,
                                                        const int* __restrict__ chunkbase, const int2* __restrict__ csr,
                                                        float* __restrict__ out) {
    int bid = blockIdx.x;            // 16384 blocks
    int xcd = bid & 7;
    int idx = bid >> 3;              // 0..2047
    int b = xcd * 2 + (idx >> 10);
    int rowblk = idx & 1023;
    int wave = threadIdx.x >> 6;
    int lane = threadIdx.x & 63;
    int n = rowblk * 4 + wave;

    const bf16x4* xw4 = reinterpret_cast<const bf16x4*>(xw + (size_t)b * NN * COUT);
    float di = dinv[b * NN + n];
    float sn = di * di;
    bf16x4 sv = xw4[(size_t)n * 64 + lane];
    float4 acc = make_float4(sn * (float)sv[0], sn * (float)sv[1], sn * (float)sv[2], sn * (float)sv[3]);

    const int* cb = chunkbase + (size_t)b * NCH * NN;   // chunk 0 row == row offsets
    int s = cb[n];
    int e = (n == NN - 1) ? EE : cb[n + 1];
    const int2* cs = csr + (size_t)b * EE;
    int i = s;
    for (; i + 4 <= e; i += 4) {
        int2 p0 = cs[i], p1 = cs[i + 1], p2 = cs[i + 2], p3 = cs[i + 3];
        bf16x4 v0 = xw4[(size_t)p0.x * 64 + lane];
        bf16x4 v1 = xw4[(size_t)p1.x * 64 + lane];
        bf16x4 v2 = xw4[(size_t)p2.x * 64 + lane];
        bf16x4 v3 = xw4[(size_t)p3.x * 64 + lane];
        float m0 = __int_as_float(p0.y), m1 = __int_as_float(p1.y);
        float m2 = __int_as_float(p2.y), m3 = __int_as_float(p3.y);
        acc.x += m0 * (float)v0[0] + m1 * (float)v1[0] + m2 * (float)v2[0] + m3 * (float)v3[0];
        acc.y += m0 * (float)v0[1] + m1 * (float)v1[1] + m2 * (float)v2[1] + m3 * (float)v3[1];
        acc.z += m0 * (float)v0[2] + m1 * (float)v1[2] + m2 * (float)v2[2] + m3 * (float)v3[2];
        acc.w += m0 * (float)v0[3] + m1 * (float)v1[3] + m2 * (float)v2[3] + m3 * (float)v3[3];
    }
    for (; i < e; ++i) {
        int2 p = cs[i];
        float nm = __int_as_float(p.y);
        bf16x4 v = xw4[(size_t)p.x * 64 + lane];
        acc.x += nm * (float)v[0]; acc.y += nm * (float)v[1];
        acc.z += nm * (float)v[2]; acc.w += nm * (float)v[3];
    }
    float4 o = make_float4(fmaxf(acc.x, 0.f), fmaxf(acc.y, 0.f), fmaxf(acc.z, 0.f), fmaxf(acc.w, 0.f));
    *reinterpret_cast<float4*>(&out[((size_t)b * NN + n) * COUT + 4 * lane]) = o;
}

// ---------------- fallback (atomic) path ----------------
__global__ __launch_bounds__(256) void deg_only_kernel(const int* __restrict__ ei, const float* __restrict__ ew,
                                                       float* __restrict__ deg) {
    int idx = blockIdx.x * 256 + threadIdx.x;
    if (idx >= BB * EE) return;
    int b = idx / EE, e = idx - b * EE;
    atomicAdd(&deg[b * NN + ei[(size_t)b * 2 * EE + e]], ew[(size_t)b * EE + e]);
}

__global__ __launch_bounds__(256) void deginv_kernel(const float* __restrict__ deg, float* __restrict__ dinv) {
    int i = blockIdx.x * 256 + threadIdx.x;
    if (i < BB * NN) {
        float d = deg[i];
        dinv[i] = (d > 0.0f) ? rsqrtf(d) : 0.0f;
    }
}

__global__ __launch_bounds__(256) void self_kernel(const __bf16* __restrict__ xw, const float* __restrict__ dinv,
                                                   float* __restrict__ out) {
    int bn = blockIdx.x;
    int c = threadIdx.x;
    float di = dinv[bn];
    out[(size_t)bn * COUT + c] = di * di * (float)xw[(size_t)bn * COUT + c];
}

__global__ __launch_bounds__(256) void scatter_atomic_kernel(const int* __restrict__ ei, const float* __restrict__ ew,
                                                             const float* __restrict__ dinv,
                                                             const __bf16* __restrict__ xw, float* __restrict__ out) {
    int be = blockIdx.x;
    int b = be / EE, e = be - b * EE;
    int c = threadIdx.x;
    int row = ei[(size_t)b * 2 * EE + e];
    int col = ei[(size_t)b * 2 * EE + EE + e];
    float w = ew[(size_t)b * EE + e];
    float nm = dinv[b * NN + row] * w * dinv[b * NN + col];
    const __bf16* xwb = xw + (size_t)b * NN * COUT;
    atomicAdd(&out[((size_t)b * NN + row) * COUT + c], nm * (float)xwb[(size_t)col * COUT + c]);
}

__global__ __launch_bounds__(256) void relu_kernel(float* __restrict__ out) {
    size_t i = (size_t)blockIdx.x * 256 + threadIdx.x;
    out[i] = fmaxf(out[i], 0.0f);
}

extern "C" void kernel_launch(void* const* d_in, const int* in_sizes, int n_in,
                              void* d_out, int out_size, void* d_ws, size_t ws_size,
                              hipStream_t stream) {
    const float* x  = (const float*)d_in[0];
    const int*   ei = (const int*)d_in[1];
    const float* ew = (const float*)d_in[2];
    const float* Wm = (const float*)d_in[3];
    float* out = (float*)d_out;

    char* ws = (char*)d_ws;
    size_t off = 0;
    auto alloc = [&](size_t bytes) -> void* {
        void* p = ws + off;
        off += (bytes + 255) & ~(size_t)255;
        return p;
    };
    __bf16* xw        = (__bf16*)alloc((size_t)BB * NN * COUT * 2);   // 32 MB
    __bf16* wt        = (__bf16*)alloc((size_t)CIN * COUT * 2);
    float*  deg       = (float*)alloc((size_t)BB * NN * 4);
    float*  dinv      = (float*)alloc((size_t)BB * NN * 4);
    int*    chunkbase = (int*)alloc((size_t)BB * NCH * NN * 4);       // 4 MB
    int2*   csr       = (int2*)alloc((size_t)BB * EE * 8);            // 16 MB
    int*    chist     = (int*)csr;  // aliases first 4 MB of csr; dead before csr is written
    bool use_csr = (ws_size >= off);

    const int bnBlocks = (BB * NN) / 256;       // 256

    cvt_wt_kernel<<<COUT, CIN, 0, stream>>>(Wm, wt);

    if (use_csr) {
        init_deg_kernel<<<bnBlocks, 256, 0, stream>>>(deg, 0.0f);
        hist_kernel<<<BB * NCH, 256, 0, stream>>>(ei, ew, chist, deg);
        scan2_kernel<<<BB, 1024, 0, stream>>>(chist, deg, chunkbase, dinv);
        dim3 ggrid((BB * NN) / 128, COUT / 128);
        gemm_mfma_kernel<<<ggrid, 256, 0, stream>>>(x, wt, xw);
        scatter2_kernel<<<BB * NCH, 256, 0, stream>>>(ei, ew, dinv, chunkbase, csr);
        aggregate_kernel<<<BB * NN / 4, 256, 0, stream>>>(xw, dinv, chunkbase, csr, out);
    } else {
        init_deg_kernel<<<bnBlocks, 256, 0, stream>>>(deg, 1.0f);
        deg_only_kernel<<<(BB * EE) / 256, 256, 0, stream>>>(ei, ew, deg);
        deginv_kernel<<<bnBlocks, 256, 0, stream>>>(deg, dinv);
        dim3 ggrid((BB * NN) / 128, COUT / 128);
        gemm_mfma_kernel<<<ggrid, 256, 0, stream>>>(x, wt, xw);
        self_kernel<<<BB * NN, 256, 0, stream>>>(xw, dinv, out);
        scatter_atomic_kernel<<<BB * EE, 256, 0, stream>>>(ei, ew, dinv, xw, out);
        relu_kernel<<<(BB * NN * COUT) / 256, 256, 0, stream>>>(out);
    }
}

// Round 4
// 168.710 us; speedup vs baseline: 3.5220x; 1.1513x over previous
//
#include <hip/hip_runtime.h>
#include <cstdint>
#include <cstddef>

#define BB 16
#define NN 4096
#define EE 131072
#define CIN 256
#define COUT 256
#define NCH 16
#define CHE (EE / NCH)   // 8192 edges per chunk

typedef __attribute__((ext_vector_type(8))) __bf16 bf16x8;
typedef __attribute__((ext_vector_type(4))) __bf16 bf16x4;
typedef __attribute__((ext_vector_type(4))) float f32x4;

// ---------------- init ----------------
__global__ __launch_bounds__(256) void init_deg_kernel(float* __restrict__ deg, float v) {
    int i = blockIdx.x * 256 + threadIdx.x;
    if (i < BB * NN) deg[i] = v;
}

// ---------------- W transpose + bf16 cast: wt[n][k] = (bf16)W[k][n] ----------------
__global__ __launch_bounds__(256) void cvt_wt_kernel(const float* __restrict__ W, __bf16* __restrict__ wt) {
    int n = blockIdx.x;
    int k = threadIdx.x;
    wt[n * CIN + k] = (__bf16)W[(size_t)k * COUT + n];
}

// ---------------- per-chunk LDS histogram: counts (exact) + weighted deg (coalesced atomic merge) ----------------
__global__ __launch_bounds__(256) void hist_kernel(const int* __restrict__ ei, const float* __restrict__ ew,
                                                   int* __restrict__ chist, float* __restrict__ deg) {
    __shared__ int h[NN];       // 16 KB
    __shared__ float wh[NN];    // 16 KB
    int b = blockIdx.x >> 4;          // /NCH
    int c = blockIdx.x & (NCH - 1);
    int tid = threadIdx.x;
    for (int i = tid; i < NN; i += 256) { h[i] = 0; wh[i] = 0.f; }
    __syncthreads();
    const int* rows = ei + (size_t)b * 2 * EE + (size_t)c * CHE;
    const float* w = ew + (size_t)b * EE + (size_t)c * CHE;
    #pragma unroll 4
    for (int j = 0; j < CHE / 256; ++j) {
        int row = rows[j * 256 + tid];
        float wv = w[j * 256 + tid];
        atomicAdd(&h[row], 1);
        atomicAdd(&wh[row], wv);
    }
    __syncthreads();
    int* co = chist + ((size_t)b * NCH + c) * NN;
    float* dg = deg + (size_t)b * NN;
    for (int i = tid; i < NN; i += 256) {
        co[i] = h[i];
        atomicAdd(&dg[i], wh[i]);   // coalesced contiguous atomics
    }
}

// ---------------- per-batch scan (shfl-based): row offsets + per-chunk bases + dinv ----------------
__global__ __launch_bounds__(1024) void scan2_kernel(const int* __restrict__ chist, const float* __restrict__ deg,
                                                     int* __restrict__ chunkbase, float* __restrict__ dinv) {
    int b = blockIdx.x, tid = threadIdx.x;
    int wid = tid >> 6, lane = tid & 63;
    __shared__ int wsum[16];
    __shared__ int wbase[16];
    __shared__ int gtot_s;
    int run[4];
    int carry = 0;
    for (int g = 0; g < 4; ++g) {
        int r = g * 1024 + tid;
        int tot = 0;
        #pragma unroll
        for (int c = 0; c < NCH; ++c) tot += chist[((size_t)b * NCH + c) * NN + r];
        dinv[b * NN + r] = rsqrtf(deg[b * NN + r] + 1.0f);   // +1 = self loop, always > 0
        int incl = tot;
        #pragma unroll
        for (int off = 1; off < 64; off <<= 1) {
            int t = __shfl_up(incl, off, 64);
            if (lane >= off) incl += t;
        }
        if (lane == 63) wsum[wid] = incl;
        __syncthreads();
        if (wid == 0) {
            int v = (lane < 16) ? wsum[lane] : 0;
            int winc = v;
            #pragma unroll
            for (int off = 1; off < 16; off <<= 1) {
                int t = __shfl_up(winc, off, 64);
                if (lane >= off) winc += t;
            }
            if (lane < 16) wbase[lane] = winc - v;   // exclusive wave base
            if (lane == 15) gtot_s = winc;           // group total
        }
        __syncthreads();
        run[g] = carry + wbase[wid] + (incl - tot);  // exclusive offset for row r
        carry += gtot_s;
    }
    for (int g = 0; g < 4; ++g) {
        int acc = run[g];
        int r = g * 1024 + tid;
        #pragma unroll
        for (int c = 0; c < NCH; ++c) {
            size_t idx = ((size_t)b * NCH + c) * NN + r;
            int t = chist[idx];
            chunkbase[idx] = acc;   // chunkbase[c=0][r] == CSR row offset
            acc += t;
        }
    }
}

// ---------------- scatter into CSR slots — LDS atomics only, XCD-pinned ----------------
// csr entry: {x = col*512 (byte offset into bf16 xw slab), y = norm bits}
__global__ __launch_bounds__(256) void scatter2_kernel(const int* __restrict__ ei, const float* __restrict__ ew,
                                                       const float* __restrict__ dinv, const int* __restrict__ chunkbase,
                                                       int2* __restrict__ csr) {
    __shared__ int basebuf[NN];     // 16 KB — running slot counters
    __shared__ float dinvs[NN];     // 16 KB
    int bid = blockIdx.x;           // 256 blocks
    int xcd = bid & 7;
    int j = bid >> 3;               // 0..31
    int b = xcd * 2 + (j >> 4);
    int c = j & (NCH - 1);
    int tid = threadIdx.x;
    for (int i = tid; i < NN; i += 256) {
        basebuf[i] = chunkbase[((size_t)b * NCH + c) * NN + i];
        dinvs[i] = dinv[b * NN + i];
    }
    __syncthreads();
    const int* rows = ei + (size_t)b * 2 * EE + (size_t)c * CHE;
    const int* cols = rows + EE;
    const float* w = ew + (size_t)b * EE + (size_t)c * CHE;
    int2* cs = csr + (size_t)b * EE;
    #pragma unroll 4
    for (int jj = 0; jj < CHE / 256; ++jj) {
        int e = jj * 256 + tid;
        int row = rows[e];
        int col = cols[e];
        float nm = dinvs[row] * w[e] * dinvs[col];
        int pos = atomicAdd(&basebuf[row], 1);
        int2 pk; pk.x = col * (COUT * 2); pk.y = __float_as_int(nm);
        cs[pos] = pk;
    }
}

// ---------------- MFMA GEMM: xw(bf16)[M][COUT] = bf16(x)[M][CIN] @ bf16(W)[CIN][COUT] ----------------
__global__ __launch_bounds__(256) void gemm_mfma_kernel(const float* __restrict__ x, const __bf16* __restrict__ wt,
                                                        __bf16* __restrict__ xw) {
    __shared__ __bf16 As[128][64];   // 16 KB
    __shared__ __bf16 Bs[128][64];   // 16 KB
    int tid = threadIdx.x;
    int lane = tid & 63;
    int wave = tid >> 6;
    int row0 = blockIdx.x * 128;
    int col0 = blockIdx.y * 128;
    int wr = wave >> 1, wc = wave & 1;
    int hi = lane >> 4, lo = lane & 15;
    f32x4 acc[4][4] = {};

    for (int kk = 0; kk < CIN; kk += 64) {
        #pragma unroll
        for (int j = 0; j < 4; ++j) {
            int c = j * 256 + tid;
            int r = c >> 3, kq = c & 7;
            const float* g = &x[(size_t)(row0 + r) * CIN + kk + 8 * kq];
            float4 f0 = *reinterpret_cast<const float4*>(g);
            float4 f1 = *reinterpret_cast<const float4*>(g + 4);
            bf16x8 v;
            v[0] = (__bf16)f0.x; v[1] = (__bf16)f0.y; v[2] = (__bf16)f0.z; v[3] = (__bf16)f0.w;
            v[4] = (__bf16)f1.x; v[5] = (__bf16)f1.y; v[6] = (__bf16)f1.z; v[7] = (__bf16)f1.w;
            *reinterpret_cast<bf16x8*>(&As[r][8 * kq]) = v;
        }
        #pragma unroll
        for (int j = 0; j < 4; ++j) {
            int c = j * 256 + tid;
            int r = c >> 3, kq = c & 7;
            *reinterpret_cast<bf16x8*>(&Bs[r][8 * kq]) =
                *reinterpret_cast<const bf16x8*>(&wt[(size_t)(col0 + r) * CIN + kk + 8 * kq]);
        }
        __syncthreads();
        #pragma unroll
        for (int ks = 0; ks < 2; ++ks) {
            bf16x8 a[4], b[4];
            #pragma unroll
            for (int m = 0; m < 4; ++m)
                a[m] = *reinterpret_cast<const bf16x8*>(&As[wr * 64 + m * 16 + lo][ks * 32 + 8 * hi]);
            #pragma unroll
            for (int n = 0; n < 4; ++n)
                b[n] = *reinterpret_cast<const bf16x8*>(&Bs[wc * 64 + n * 16 + lo][ks * 32 + 8 * hi]);
            #pragma unroll
            for (int m = 0; m < 4; ++m)
                #pragma unroll
                for (int n = 0; n < 4; ++n)
                    acc[m][n] = __builtin_amdgcn_mfma_f32_16x16x32_bf16(a[m], b[n], acc[m][n], 0, 0, 0);
        }
        __syncthreads();
    }
    #pragma unroll
    for (int m = 0; m < 4; ++m)
        #pragma unroll
        for (int n = 0; n < 4; ++n)
            #pragma unroll
            for (int r = 0; r < 4; ++r) {
                int row = row0 + wr * 64 + m * 16 + hi * 4 + r;
                int col = col0 + wc * 64 + n * 16 + lo;
                xw[(size_t)row * COUT + col] = (__bf16)acc[m][n][r];
            }
}

// ---------------- CSR aggregation: LDS-staged CSR + saddr gathers + 8x unroll ----------------
__global__ __launch_bounds__(256) void aggregate_kernel(const __bf16* __restrict__ xw, const float* __restrict__ dinv,
                                                        const int* __restrict__ chunkbase, const int2* __restrict__ csr,
                                                        float* __restrict__ out) {
    __shared__ int2 ebuf[2048];      // 16 KB — block's CSR slice (rows are contiguous in CSR)
    int bid = blockIdx.x;            // 16384 blocks
    int xcd = bid & 7;
    int idx = bid >> 3;              // 0..2047
    int b = xcd * 2 + (idx >> 10);
    int rowblk = idx & 1023;
    int tid = threadIdx.x;
    int wave = tid >> 6;
    int lane = tid & 63;
    int n0 = rowblk * 4;
    int n = n0 + wave;

    const int* cb = chunkbase + (size_t)b * NCH * NN;   // chunk-0 row == CSR row offsets
    int s0 = cb[n0];
    int e3 = (n0 + 4 == NN) ? EE : cb[n0 + 4];
    int cnt = e3 - s0;
    int staged = min(cnt, 2048);
    const int2* cs = csr + (size_t)b * EE;
    for (int i = tid; i < staged; i += 256) ebuf[i] = cs[s0 + i];

    const char* xwb = (const char*)(xw + (size_t)b * NN * COUT) + lane * 8;
    float di = dinv[b * NN + n];
    float sn = di * di;
    bf16x4 sv = *reinterpret_cast<const bf16x4*>(xwb + n * (COUT * 2));
    float4 acc = make_float4(sn * (float)sv[0], sn * (float)sv[1], sn * (float)sv[2], sn * (float)sv[3]);

    int sL = cb[n] - s0;
    int eL = ((n == NN - 1) ? EE : cb[n + 1]) - s0;
    __syncthreads();

    int i = sL;
    for (; i + 8 <= eL; i += 8) {
        int2 q[8];
        if (i + 8 <= staged) {
            #pragma unroll
            for (int u = 0; u < 8; ++u) q[u] = ebuf[i + u];
        } else {
            #pragma unroll
            for (int u = 0; u < 8; ++u) q[u] = cs[s0 + i + u];
        }
        bf16x4 v[8];
        #pragma unroll
        for (int u = 0; u < 8; ++u) v[u] = *reinterpret_cast<const bf16x4*>(xwb + q[u].x);
        #pragma unroll
        for (int u = 0; u < 8; ++u) {
            float nm = __int_as_float(q[u].y);
            acc.x += nm * (float)v[u][0];
            acc.y += nm * (float)v[u][1];
            acc.z += nm * (float)v[u][2];
            acc.w += nm * (float)v[u][3];
        }
    }
    for (; i < eL; ++i) {
        int2 q = (i < staged) ? ebuf[i] : cs[s0 + i];
        bf16x4 v = *reinterpret_cast<const bf16x4*>(xwb + q.x);
        float nm = __int_as_float(q.y);
        acc.x += nm * (float)v[0]; acc.y += nm * (float)v[1];
        acc.z += nm * (float)v[2]; acc.w += nm * (float)v[3];
    }
    float4 o = make_float4(fmaxf(acc.x, 0.f), fmaxf(acc.y, 0.f), fmaxf(acc.z, 0.f), fmaxf(acc.w, 0.f));
    *reinterpret_cast<float4*>(&out[((size_t)b * NN + n) * COUT + 4 * lane]) = o;
}

// ---------------- fallback (atomic) path ----------------
__global__ __launch_bounds__(256) void deg_only_kernel(const int* __restrict__ ei, const float* __restrict__ ew,
                                                       float* __restrict__ deg) {
    int idx = blockIdx.x * 256 + threadIdx.x;
    if (idx >= BB * EE) return;
    int b = idx / EE, e = idx - b * EE;
    atomicAdd(&deg[b * NN + ei[(size_t)b * 2 * EE + e]], ew[(size_t)b * EE + e]);
}

__global__ __launch_bounds__(256) void deginv_kernel(const float* __restrict__ deg, float* __restrict__ dinv) {
    int i = blockIdx.x * 256 + threadIdx.x;
    if (i < BB * NN) {
        float d = deg[i];
        dinv[i] = (d > 0.0f) ? rsqrtf(d) : 0.0f;
    }
}

__global__ __launch_bounds__(256) void self_kernel(const __bf16* __restrict__ xw, const float* __restrict__ dinv,
                                                   float* __restrict__ out) {
    int bn = blockIdx.x;
    int c = threadIdx.x;
    float di = dinv[bn];
    out[(size_t)bn * COUT + c] = di * di * (float)xw[(size_t)bn * COUT + c];
}

__global__ __launch_bounds__(256) void scatter_atomic_kernel(const int* __restrict__ ei, const float* __restrict__ ew,
                                                             const float* __restrict__ dinv,
                                                             const __bf16* __restrict__ xw, float* __restrict__ out) {
    int be = blockIdx.x;
    int b = be / EE, e = be - b * EE;
    int c = threadIdx.x;
    int row = ei[(size_t)b * 2 * EE + e];
    int col = ei[(size_t)b * 2 * EE + EE + e];
    float w = ew[(size_t)b * EE + e];
    float nm = dinv[b * NN + row] * w * dinv[b * NN + col];
    const __bf16* xwb = xw + (size_t)b * NN * COUT;
    atomicAdd(&out[((size_t)b * NN + row) * COUT + c], nm * (float)xwb[(size_t)col * COUT + c]);
}

__global__ __launch_bounds__(256) void relu_kernel(float* __restrict__ out) {
    size_t i = (size_t)blockIdx.x * 256 + threadIdx.x;
    out[i] = fmaxf(out[i], 0.0f);
}

extern "C" void kernel_launch(void* const* d_in, const int* in_sizes, int n_in,
                              void* d_out, int out_size, void* d_ws, size_t ws_size,
                              hipStream_t stream) {
    const float* x  = (const float*)d_in[0];
    const int*   ei = (const int*)d_in[1];
    const float* ew = (const float*)d_in[2];
    const float* Wm = (const float*)d_in[3];
    float* out = (float*)d_out;

    char* ws = (char*)d_ws;
    size_t off = 0;
    auto alloc = [&](size_t bytes) -> void* {
        void* p = ws + off;
        off += (bytes + 255) & ~(size_t)255;
        return p;
    };
    __bf16* xw        = (__bf16*)alloc((size_t)BB * NN * COUT * 2);   // 32 MB
    __bf16* wt        = (__bf16*)alloc((size_t)CIN * COUT * 2);
    float*  deg       = (float*)alloc((size_t)BB * NN * 4);
    float*  dinv      = (float*)alloc((size_t)BB * NN * 4);
    int*    chunkbase = (int*)alloc((size_t)BB * NCH * NN * 4);       // 4 MB
    int2*   csr       = (int2*)alloc((size_t)BB * EE * 8);            // 16 MB
    int*    chist     = (int*)csr;  // aliases first 4 MB of csr; dead before csr is written
    bool use_csr = (ws_size >= off);

    const int bnBlocks = (BB * NN) / 256;       // 256

    cvt_wt_kernel<<<COUT, CIN, 0, stream>>>(Wm, wt);

    if (use_csr) {
        init_deg_kernel<<<bnBlocks, 256, 0, stream>>>(deg, 0.0f);
        hist_kernel<<<BB * NCH, 256, 0, stream>>>(ei, ew, chist, deg);
        scan2_kernel<<<BB, 1024, 0, stream>>>(chist, deg, chunkbase, dinv);
        dim3 ggrid((BB * NN) / 128, COUT / 128);
        gemm_mfma_kernel<<<ggrid, 256, 0, stream>>>(x, wt, xw);
        scatter2_kernel<<<BB * NCH, 256, 0, stream>>>(ei, ew, dinv, chunkbase, csr);
        aggregate_kernel<<<BB * NN / 4, 256, 0, stream>>>(xw, dinv, chunkbase, csr, out);
    } else {
        init_deg_kernel<<<bnBlocks, 256, 0, stream>>>(deg, 1.0f);
        deg_only_kernel<<<(BB * EE) / 256, 256, 0, stream>>>(ei, ew, deg);
        deginv_kernel<<<bnBlocks, 256, 0, stream>>>(deg, dinv);
        dim3 ggrid((BB * NN) / 128, COUT / 128);
        gemm_mfma_kernel<<<ggrid, 256, 0, stream>>>(x, wt, xw);
        self_kernel<<<BB * NN, 256, 0, stream>>>(xw, dinv, out);
        scatter_atomic_kernel<<<BB * EE, 256, 0, stream>>>(ei, ew, dinv, xw, out);
        relu_kernel<<<(BB * NN * COUT) / 256, 256, 0, stream>>>(out);
    }
}

// Round 5
// 160.776 us; speedup vs baseline: 3.6958x; 1.0494x over previous
//
#include <hip/hip_runtime.h>
#include <cstdint>
#include <cstddef>

#define BB 16
#define NN 4096
#define EE 131072
#define CIN 256
#define COUT 256
#define NCH 16
#define CHE (EE / NCH)   // 8192 edges per chunk

typedef __attribute__((ext_vector_type(8))) __bf16 bf16x8;
typedef __attribute__((ext_vector_type(4))) __bf16 bf16x4;
typedef __attribute__((ext_vector_type(4))) float f32x4;
typedef __attribute__((ext_vector_type(2))) float f32x2;

// ---------------- init ----------------
__global__ __launch_bounds__(256) void init_deg_kernel(float* __restrict__ deg, float v) {
    int i = blockIdx.x * 256 + threadIdx.x;
    if (i < BB * NN) deg[i] = v;
}

// ---------------- W transpose + bf16 cast: wt[n][k] = (bf16)W[k][n] ----------------
__global__ __launch_bounds__(256) void cvt_wt_kernel(const float* __restrict__ W, __bf16* __restrict__ wt) {
    int n = blockIdx.x;
    int k = threadIdx.x;
    wt[n * CIN + k] = (__bf16)W[(size_t)k * COUT + n];
}

// ---------------- per-chunk LDS histogram: counts (exact) + weighted deg (coalesced atomic merge) ----------------
__global__ __launch_bounds__(256) void hist_kernel(const int* __restrict__ ei, const float* __restrict__ ew,
                                                   int* __restrict__ chist, float* __restrict__ deg) {
    __shared__ int h[NN];       // 16 KB
    __shared__ float wh[NN];    // 16 KB
    int b = blockIdx.x >> 4;          // /NCH
    int c = blockIdx.x & (NCH - 1);
    int tid = threadIdx.x;
    for (int i = tid; i < NN; i += 256) { h[i] = 0; wh[i] = 0.f; }
    __syncthreads();
    const int* rows = ei + (size_t)b * 2 * EE + (size_t)c * CHE;
    const float* w = ew + (size_t)b * EE + (size_t)c * CHE;
    #pragma unroll 4
    for (int j = 0; j < CHE / 256; ++j) {
        int row = rows[j * 256 + tid];
        float wv = w[j * 256 + tid];
        atomicAdd(&h[row], 1);
        atomicAdd(&wh[row], wv);
    }
    __syncthreads();
    int* co = chist + ((size_t)b * NCH + c) * NN;
    float* dg = deg + (size_t)b * NN;
    for (int i = tid; i < NN; i += 256) {
        co[i] = h[i];
        atomicAdd(&dg[i], wh[i]);   // coalesced contiguous atomics
    }
}

// ---------------- per-batch scan (shfl-based): row offsets + per-chunk bases + dinv ----------------
__global__ __launch_bounds__(1024) void scan2_kernel(const int* __restrict__ chist, const float* __restrict__ deg,
                                                     int* __restrict__ chunkbase, float* __restrict__ dinv) {
    int b = blockIdx.x, tid = threadIdx.x;
    int wid = tid >> 6, lane = tid & 63;
    __shared__ int wsum[16];
    __shared__ int wbase[16];
    __shared__ int gtot_s;
    int run[4];
    int carry = 0;
    for (int g = 0; g < 4; ++g) {
        int r = g * 1024 + tid;
        int tot = 0;
        #pragma unroll
        for (int c = 0; c < NCH; ++c) tot += chist[((size_t)b * NCH + c) * NN + r];
        dinv[b * NN + r] = rsqrtf(deg[b * NN + r] + 1.0f);   // +1 = self loop, always > 0
        int incl = tot;
        #pragma unroll
        for (int off = 1; off < 64; off <<= 1) {
            int t = __shfl_up(incl, off, 64);
            if (lane >= off) incl += t;
        }
        if (lane == 63) wsum[wid] = incl;
        __syncthreads();
        if (wid == 0) {
            int v = (lane < 16) ? wsum[lane] : 0;
            int winc = v;
            #pragma unroll
            for (int off = 1; off < 16; off <<= 1) {
                int t = __shfl_up(winc, off, 64);
                if (lane >= off) winc += t;
            }
            if (lane < 16) wbase[lane] = winc - v;   // exclusive wave base
            if (lane == 15) gtot_s = winc;           // group total
        }
        __syncthreads();
        run[g] = carry + wbase[wid] + (incl - tot);  // exclusive offset for row r
        carry += gtot_s;
    }
    for (int g = 0; g < 4; ++g) {
        int acc = run[g];
        int r = g * 1024 + tid;
        #pragma unroll
        for (int c = 0; c < NCH; ++c) {
            size_t idx = ((size_t)b * NCH + c) * NN + r;
            int t = chist[idx];
            chunkbase[idx] = acc;   // chunkbase[c=0][r] == CSR row offset
            acc += t;
        }
    }
}

// ---------------- scatter into CSR slots — LDS atomics only, XCD-pinned ----------------
// csr entry: {x = col*512 (byte offset into bf16 xw slab), y = norm bits}
__global__ __launch_bounds__(256) void scatter2_kernel(const int* __restrict__ ei, const float* __restrict__ ew,
                                                       const float* __restrict__ dinv, const int* __restrict__ chunkbase,
                                                       int2* __restrict__ csr) {
    __shared__ int basebuf[NN];     // 16 KB — running slot counters
    __shared__ float dinvs[NN];     // 16 KB
    int bid = blockIdx.x;           // 256 blocks
    int xcd = bid & 7;
    int j = bid >> 3;               // 0..31
    int b = xcd * 2 + (j >> 4);
    int c = j & (NCH - 1);
    int tid = threadIdx.x;
    for (int i = tid; i < NN; i += 256) {
        basebuf[i] = chunkbase[((size_t)b * NCH + c) * NN + i];
        dinvs[i] = dinv[b * NN + i];
    }
    __syncthreads();
    const int* rows = ei + (size_t)b * 2 * EE + (size_t)c * CHE;
    const int* cols = rows + EE;
    const float* w = ew + (size_t)b * EE + (size_t)c * CHE;
    int2* cs = csr + (size_t)b * EE;
    #pragma unroll 4
    for (int jj = 0; jj < CHE / 256; ++jj) {
        int e = jj * 256 + tid;
        int row = rows[e];
        int col = cols[e];
        float nm = dinvs[row] * w[e] * dinvs[col];
        int pos = atomicAdd(&basebuf[row], 1);
        int2 pk; pk.x = col * (COUT * 2); pk.y = __float_as_int(nm);
        cs[pos] = pk;
    }
}

// ---------------- MFMA GEMM: xw(bf16)[M][COUT] = bf16(x)[M][CIN] @ bf16(W)[CIN][COUT] ----------------
__global__ __launch_bounds__(256) void gemm_mfma_kernel(const float* __restrict__ x, const __bf16* __restrict__ wt,
                                                        __bf16* __restrict__ xw) {
    __shared__ __bf16 As[128][64];   // 16 KB
    __shared__ __bf16 Bs[128][64];   // 16 KB
    int tid = threadIdx.x;
    int lane = tid & 63;
    int wave = tid >> 6;
    int row0 = blockIdx.x * 128;
    int col0 = blockIdx.y * 128;
    int wr = wave >> 1, wc = wave & 1;
    int hi = lane >> 4, lo = lane & 15;
    f32x4 acc[4][4] = {};

    for (int kk = 0; kk < CIN; kk += 64) {
        #pragma unroll
        for (int j = 0; j < 4; ++j) {
            int c = j * 256 + tid;
            int r = c >> 3, kq = c & 7;
            const float* g = &x[(size_t)(row0 + r) * CIN + kk + 8 * kq];
            float4 f0 = *reinterpret_cast<const float4*>(g);
            float4 f1 = *reinterpret_cast<const float4*>(g + 4);
            bf16x8 v;
            v[0] = (__bf16)f0.x; v[1] = (__bf16)f0.y; v[2] = (__bf16)f0.z; v[3] = (__bf16)f0.w;
            v[4] = (__bf16)f1.x; v[5] = (__bf16)f1.y; v[6] = (__bf16)f1.z; v[7] = (__bf16)f1.w;
            *reinterpret_cast<bf16x8*>(&As[r][8 * kq]) = v;
        }
        #pragma unroll
        for (int j = 0; j < 4; ++j) {
            int c = j * 256 + tid;
            int r = c >> 3, kq = c & 7;
            *reinterpret_cast<bf16x8*>(&Bs[r][8 * kq]) =
                *reinterpret_cast<const bf16x8*>(&wt[(size_t)(col0 + r) * CIN + kk + 8 * kq]);
        }
        __syncthreads();
        #pragma unroll
        for (int ks = 0; ks < 2; ++ks) {
            bf16x8 a[4], b[4];
            #pragma unroll
            for (int m = 0; m < 4; ++m)
                a[m] = *reinterpret_cast<const bf16x8*>(&As[wr * 64 + m * 16 + lo][ks * 32 + 8 * hi]);
            #pragma unroll
            for (int n = 0; n < 4; ++n)
                b[n] = *reinterpret_cast<const bf16x8*>(&Bs[wc * 64 + n * 16 + lo][ks * 32 + 8 * hi]);
            #pragma unroll
            for (int m = 0; m < 4; ++m)
                #pragma unroll
                for (int n = 0; n < 4; ++n)
                    acc[m][n] = __builtin_amdgcn_mfma_f32_16x16x32_bf16(a[m], b[n], acc[m][n], 0, 0, 0);
        }
        __syncthreads();
    }
    #pragma unroll
    for (int m = 0; m < 4; ++m)
        #pragma unroll
        for (int n = 0; n < 4; ++n)
            #pragma unroll
            for (int r = 0; r < 4; ++r) {
                int row = row0 + wr * 64 + m * 16 + hi * 4 + r;
                int col = col0 + wc * 64 + n * 16 + lo;
                xw[(size_t)row * COUT + col] = (__bf16)acc[m][n][r];
            }
}

// ---------------- CSR aggregation: scalar CSR reads (wave-uniform) + pk-fma math, no LDS ----------------
__global__ __launch_bounds__(256) void aggregate_kernel(const __bf16* __restrict__ xw, const float* __restrict__ dinv,
                                                        const int* __restrict__ chunkbase, const int2* __restrict__ csr,
                                                        float* __restrict__ out) {
    int bid = blockIdx.x;            // 16384 blocks
    int xcd = bid & 7;
    int idx = bid >> 3;              // 0..2047
    int b = xcd * 2 + (idx >> 10);
    int rowblk = idx & 1023;
    int wave = threadIdx.x >> 6;
    int lane = threadIdx.x & 63;
    int n = rowblk * 4 + wave;

    const int* cb = chunkbase + (size_t)b * NCH * NN;   // chunk-0 row == CSR row offsets
    int s = __builtin_amdgcn_readfirstlane(cb[n]);
    int eRaw = (n == NN - 1) ? EE : cb[n + 1];
    int e = __builtin_amdgcn_readfirstlane(eRaw);
    int cnt = e - s;
    const int2* cs = csr + (size_t)b * EE + s;          // wave-uniform base

    const char* xwb = (const char*)(xw + (size_t)b * NN * COUT) + lane * 8;
    float di = dinv[b * NN + n];
    float sn = di * di;
    uint2 sraw = *reinterpret_cast<const uint2*>(xwb + n * (COUT * 2));
    f32x2 acc01, acc23;
    acc01.x = sn * __uint_as_float(sraw.x << 16);
    acc01.y = sn * __uint_as_float(sraw.x & 0xffff0000u);
    acc23.x = sn * __uint_as_float(sraw.y << 16);
    acc23.y = sn * __uint_as_float(sraw.y & 0xffff0000u);

    int i = 0;
    for (; i + 8 <= cnt; i += 8) {
        int2 q[8];
        #pragma unroll
        for (int u = 0; u < 8; ++u) q[u] = cs[i + u];   // wave-uniform -> scalar loads
        uint2 raw[8];
        #pragma unroll
        for (int u = 0; u < 8; ++u) raw[u] = *reinterpret_cast<const uint2*>(xwb + q[u].x);
        #pragma unroll
        for (int u = 0; u < 8; ++u) {
            float nm = __int_as_float(q[u].y);
            f32x2 v01, v23;
            v01.x = __uint_as_float(raw[u].x << 16);
            v01.y = __uint_as_float(raw[u].x & 0xffff0000u);
            v23.x = __uint_as_float(raw[u].y << 16);
            v23.y = __uint_as_float(raw[u].y & 0xffff0000u);
            acc01 += nm * v01;
            acc23 += nm * v23;
        }
    }
    for (; i < cnt; ++i) {
        int2 q = cs[i];
        uint2 raw = *reinterpret_cast<const uint2*>(xwb + q.x);
        float nm = __int_as_float(q.y);
        f32x2 v01, v23;
        v01.x = __uint_as_float(raw.x << 16);
        v01.y = __uint_as_float(raw.x & 0xffff0000u);
        v23.x = __uint_as_float(raw.y << 16);
        v23.y = __uint_as_float(raw.y & 0xffff0000u);
        acc01 += nm * v01;
        acc23 += nm * v23;
    }
    float4 o = make_float4(fmaxf(acc01.x, 0.f), fmaxf(acc01.y, 0.f), fmaxf(acc23.x, 0.f), fmaxf(acc23.y, 0.f));
    *reinterpret_cast<float4*>(&out[((size_t)b * NN + n) * COUT + 4 * lane]) = o;
}

// ---------------- fallback (atomic) path ----------------
__global__ __launch_bounds__(256) void deg_only_kernel(const int* __restrict__ ei, const float* __restrict__ ew,
                                                       float* __restrict__ deg) {
    int idx = blockIdx.x * 256 + threadIdx.x;
    if (idx >= BB * EE) return;
    int b = idx / EE, e = idx - b * EE;
    atomicAdd(&deg[b * NN + ei[(size_t)b * 2 * EE + e]], ew[(size_t)b * EE + e]);
}

__global__ __launch_bounds__(256) void deginv_kernel(const float* __restrict__ deg, float* __restrict__ dinv) {
    int i = blockIdx.x * 256 + threadIdx.x;
    if (i < BB * NN) {
        float d = deg[i];
        dinv[i] = (d > 0.0f) ? rsqrtf(d) : 0.0f;
    }
}

__global__ __launch_bounds__(256) void self_kernel(const __bf16* __restrict__ xw, const float* __restrict__ dinv,
                                                   float* __restrict__ out) {
    int bn = blockIdx.x;
    int c = threadIdx.x;
    float di = dinv[bn];
    out[(size_t)bn * COUT + c] = di * di * (float)xw[(size_t)bn * COUT + c];
}

__global__ __launch_bounds__(256) void scatter_atomic_kernel(const int* __restrict__ ei, const float* __restrict__ ew,
                                                             const float* __restrict__ dinv,
                                                             const __bf16* __restrict__ xw, float* __restrict__ out) {
    int be = blockIdx.x;
    int b = be / EE, e = be - b * EE;
    int c = threadIdx.x;
    int row = ei[(size_t)b * 2 * EE + e];
    int col = ei[(size_t)b * 2 * EE + EE + e];
    float w = ew[(size_t)b * EE + e];
    float nm = dinv[b * NN + row] * w * dinv[b * NN + col];
    const __bf16* xwb = xw + (size_t)b * NN * COUT;
    atomicAdd(&out[((size_t)b * NN + row) * COUT + c], nm * (float)xwb[(size_t)col * COUT + c]);
}

__global__ __launch_bounds__(256) void relu_kernel(float* __restrict__ out) {
    size_t i = (size_t)blockIdx.x * 256 + threadIdx.x;
    out[i] = fmaxf(out[i], 0.0f);
}

extern "C" void kernel_launch(void* const* d_in, const int* in_sizes, int n_in,
                              void* d_out, int out_size, void* d_ws, size_t ws_size,
                              hipStream_t stream) {
    const float* x  = (const float*)d_in[0];
    const int*   ei = (const int*)d_in[1];
    const float* ew = (const float*)d_in[2];
    const float* Wm = (const float*)d_in[3];
    float* out = (float*)d_out;

    char* ws = (char*)d_ws;
    size_t off = 0;
    auto alloc = [&](size_t bytes) -> void* {
        void* p = ws + off;
        off += (bytes + 255) & ~(size_t)255;
        return p;
    };
    __bf16* xw        = (__bf16*)alloc((size_t)BB * NN * COUT * 2);   // 32 MB
    __bf16* wt        = (__bf16*)alloc((size_t)CIN * COUT * 2);
    float*  deg       = (float*)alloc((size_t)BB * NN * 4);
    float*  dinv      = (float*)alloc((size_t)BB * NN * 4);
    int*    chunkbase = (int*)alloc((size_t)BB * NCH * NN * 4);       // 4 MB
    int2*   csr       = (int2*)alloc((size_t)BB * EE * 8);            // 16 MB
    int*    chist     = (int*)csr;  // aliases first 4 MB of csr; dead before csr is written
    bool use_csr = (ws_size >= off);

    const int bnBlocks = (BB * NN) / 256;       // 256

    cvt_wt_kernel<<<COUT, CIN, 0, stream>>>(Wm, wt);

    if (use_csr) {
        init_deg_kernel<<<bnBlocks, 256, 0, stream>>>(deg, 0.0f);
        hist_kernel<<<BB * NCH, 256, 0, stream>>>(ei, ew, chist, deg);
        scan2_kernel<<<BB, 1024, 0, stream>>>(chist, deg, chunkbase, dinv);
        dim3 ggrid((BB * NN) / 128, COUT / 128);
        gemm_mfma_kernel<<<ggrid, 256, 0, stream>>>(x, wt, xw);
        scatter2_kernel<<<BB * NCH, 256, 0, stream>>>(ei, ew, dinv, chunkbase, csr);
        aggregate_kernel<<<BB * NN / 4, 256, 0, stream>>>(xw, dinv, chunkbase, csr, out);
    } else {
        init_deg_kernel<<<bnBlocks, 256, 0, stream>>>(deg, 1.0f);
        deg_only_kernel<<<(BB * EE) / 256, 256, 0, stream>>>(ei, ew, deg);
        deginv_kernel<<<bnBlocks, 256, 0, stream>>>(deg, dinv);
        dim3 ggrid((BB * NN) / 128, COUT / 128);
        gemm_mfma_kernel<<<ggrid, 256, 0, stream>>>(x, wt, xw);
        self_kernel<<<BB * NN, 256, 0, stream>>>(xw, dinv, out);
        scatter_atomic_kernel<<<BB * EE, 256, 0, stream>>>(ei, ew, dinv, xw, out);
        relu_kernel<<<(BB * NN * COUT) / 256, 256, 0, stream>>>(out);
    }
}